// Round 7
// baseline (274.629 us; speedup 1.0000x reference)
//
#include <hip/hip_runtime.h>

// PopulationODE: explicit Euler, L=512, B=32768, 4 states, 21 weights.
// Output [L,4,B] fp32 = 256 MiB -> write-once stream (harness fill: 6.6 TB/s).
//
// Kernel-only history (dur_us - ~163us harness fill):
//   R0 ~110us (2 waves/CU, live-reg stores)     R1-K2 ~108us (32 waves/CU!)
//   R3 ~102us (reg-staging pipe)                R4 ~104us (producer/consumer)
//   R6 ~102us (1KB dwordx4 granules)
//   => occupancy, store width, granularity, barriers ALL eliminated;
//      every variant pins at ~2.5 TB/s of cached writes. Remaining common
//      factor: stores allocate dirty L2/LLC lines for a zero-reuse 256 MiB
//      stream -> cache absorb+evict path is the suspect.
// R7 = R3 + NONTEMPORAL stores: nt-flagged stores bypass L2/L3 allocation
//   and write-combine to HBM. Only the store path changes vs R3.

#define ODE_L 512
#define ODE_B 32768
#define G     8   // steps per staging group (32 stores in flight per group)

// One Euler step (identical arithmetic to the verified R0/R3 kernels).
#define ODE_STEP(h)                                                          \
  do {                                                                       \
    const float dA = w0  + w1  * A + w2  * A * A;                            \
    const float dT = w3  + w4  * T + w5  * T * T + w6  * A + w7  * A * A +   \
                     w8  * A * T;                                            \
    const float dN = w9  + w10 * N + w11 * N * N + w12 * T + w13 * T * T +   \
                     w14 * T * N;                                            \
    const float dC = w15 + w16 * C + w17 * C * C + w18 * N + w19 * N * N +   \
                     w20 * N * C;                                            \
    A += h * dA; T += h * dT; N += h * dN; C += h * dC;                      \
  } while (0)

// Compute G steps starting at row R0V into staging half OFS (compile-time),
// then issue the 4*G nontemporal stores.
#define ODE_GROUP(OFS, R0V)                                                  \
  do {                                                                       \
    _Pragma("unroll")                                                        \
    for (int j = 0; j < G; ++j) {                                            \
      const float h = sh_h[(R0V) + j - 1];                                   \
      ODE_STEP(h);                                                           \
      bA[(OFS) + j] = A; bT[(OFS) + j] = T;                                  \
      bN[(OFS) + j] = N; bC[(OFS) + j] = C;                                  \
    }                                                                        \
    _Pragma("unroll")                                                        \
    for (int j = 0; j < G; ++j) {                                            \
      const unsigned o = ((R0V) + j) * (4u * ODE_B) + b;                     \
      __builtin_nontemporal_store(bA[(OFS) + j], &out[o + 0u * ODE_B]);      \
      __builtin_nontemporal_store(bT[(OFS) + j], &out[o + 1u * ODE_B]);      \
      __builtin_nontemporal_store(bN[(OFS) + j], &out[o + 2u * ODE_B]);      \
      __builtin_nontemporal_store(bC[(OFS) + j], &out[o + 3u * ODE_B]);      \
    }                                                                        \
  } while (0)

__global__ __launch_bounds__(64) void population_ode_kernel(
    const float* __restrict__ s_grid,   // [L]
    const float* __restrict__ y0,       // [4, B]
    const float* __restrict__ w,        // [21]
    float* __restrict__ out)            // [L, 4, B]
{
    __shared__ float sh_h[ODE_L - 1];   // h[i] = s[i+1] - s[i]

    const int tid = threadIdx.x;
    #pragma unroll
    for (int i = tid; i < ODE_L - 1; i += 64) {
        sh_h[i] = s_grid[i + 1] - s_grid[i];
    }

    // Uniform weights -> scalar loads / SGPRs.
    const float w0  = w[0],  w1  = w[1],  w2  = w[2];
    const float w3  = w[3],  w4  = w[4],  w5  = w[5],  w6  = w[6],  w7 = w[7],
                w8  = w[8];
    const float w9  = w[9],  w10 = w[10], w11 = w[11], w12 = w[12],
                w13 = w[13], w14 = w[14];
    const float w15 = w[15], w16 = w[16], w17 = w[17], w18 = w[18],
                w19 = w[19], w20 = w[20];

    __syncthreads();

    const unsigned b = blockIdx.x * 64u + (unsigned)tid;

    float A = y0[0 * ODE_B + b];
    float T = y0[1 * ODE_B + b];
    float N = y0[2 * ODE_B + b];
    float C = y0[3 * ODE_B + b];

    // Row 0 is y0 itself.
    __builtin_nontemporal_store(A, &out[0u * ODE_B + b]);
    __builtin_nontemporal_store(T, &out[1u * ODE_B + b]);
    __builtin_nontemporal_store(N, &out[2u * ODE_B + b]);
    __builtin_nontemporal_store(C, &out[3u * ODE_B + b]);

    // Double-buffered staging registers: two halves of G rows each.
    float bA[2 * G], bT[2 * G], bN[2 * G], bC[2 * G];

    // Rows 1..496: 31 iterations x 2 groups of 8 (statically indexed halves).
    for (unsigned g = 0; g < 31; ++g) {
        const unsigned r0 = 1u + g * (2 * G);
        ODE_GROUP(0, r0);
        ODE_GROUP(G, r0 + G);
    }

    // Rows 497..504: one more full group (half 0).
    ODE_GROUP(0, 497u);

    // Tail rows 505..511 (7 steps) into half 1.
    #pragma unroll
    for (int j = 0; j < 7; ++j) {
        const float h = sh_h[504 + j];
        ODE_STEP(h);
        bA[G + j] = A; bT[G + j] = T; bN[G + j] = N; bC[G + j] = C;
    }
    #pragma unroll
    for (int j = 0; j < 7; ++j) {
        const unsigned o = (505u + j) * (4u * ODE_B) + b;
        __builtin_nontemporal_store(bA[G + j], &out[o + 0u * ODE_B]);
        __builtin_nontemporal_store(bT[G + j], &out[o + 1u * ODE_B]);
        __builtin_nontemporal_store(bN[G + j], &out[o + 2u * ODE_B]);
        __builtin_nontemporal_store(bC[G + j], &out[o + 3u * ODE_B]);
    }
}

extern "C" void kernel_launch(void* const* d_in, const int* in_sizes, int n_in,
                              void* d_out, int out_size, void* d_ws, size_t ws_size,
                              hipStream_t stream) {
    (void)in_sizes; (void)n_in; (void)d_ws; (void)ws_size; (void)out_size;

    const float* s_grid = (const float*)d_in[0];
    const float* y0     = (const float*)d_in[1];
    const float* w      = (const float*)d_in[2];
    float* out          = (float*)d_out;

    // One thread per trajectory: 512 blocks x 64 threads = 512 waves (2/CU).
    population_ode_kernel<<<dim3(ODE_B / 64), dim3(64), 0, stream>>>(
        s_grid, y0, w, out);
}